// Round 3
// baseline (686.895 us; speedup 1.0000x reference)
//
#include <hip/hip_runtime.h>
#include <math.h>

#define IC     2401
#define BSZ    256
#define OC     8
#define CS     16
#define OCC    128     // OC*CS
#define XROW   19208   // x row length (floats) = IC*8
#define KP     19264   // padded K (=301*64 = 2408 granules of 8), pad zeroed
#define KTILES 301
#define NI     128     // split-K slices for s phase
#define NBLK   512     // persistent grid: 4 bg * NI, 2 blocks/CU

typedef __attribute__((ext_vector_type(8))) short short8;
typedef __attribute__((ext_vector_type(4))) float f32x4;

__device__ __forceinline__ unsigned short f2bf(float f) {
    union { float f; unsigned u; } v; v.f = f;
    const unsigned r = v.u + 0x7FFF + ((v.u >> 16) & 1);   // RNE
    return (unsigned short)(r >> 16);
}
__device__ __forceinline__ float bf2f(unsigned short h) {
    union { unsigned u; float f; } v; v.u = ((unsigned)h) << 16;
    return v.f;
}

// ---------------- prep (one launch): blocks 0..1203 -> xT + xB ; 1204..1504 -> Wbf + cwt0
__global__ __launch_bounds__(256)
void prep_kernel(const float* __restrict__ x, const float* __restrict__ W,
                 unsigned short* __restrict__ xT, unsigned short* __restrict__ xB,
                 unsigned short* __restrict__ Wbf, unsigned short* __restrict__ cwt,
                 unsigned* __restrict__ bar)
{
    const int tid = threadIdx.x;
    if (blockIdx.x == 0 && tid == 0) *bar = 0;   // reset grid-barrier counter each replay
    if (blockIdx.x < 1204) {
        __shared__ float Ts[64 * 65];
        const int bg = blockIdx.x & 3;       // b-group of 64
        const int kt = blockIdx.x >> 2;      // k-tile 0..300
#pragma unroll
        for (int r = 0; r < 4; ++r) {
            const int flat = r * 256 + tid;  // 1024 float4s
            const int b = flat >> 4, cq = flat & 15;
            const int col = kt * 64 + cq * 4;
            float4 v = make_float4(0.f, 0.f, 0.f, 0.f);
            if (col < XROW) v = *(const float4*)(x + (size_t)(bg * 64 + b) * XROW + col);
            *(float4*)&Ts[b * 65 + cq * 4] = v;
        }
        __syncthreads();
        // xT[k][b] (transposed)
#pragma unroll
        for (int r = 0; r < 2; ++r) {
            const int flat = r * 256 + tid;  // 512 granules
            const int rl = flat >> 3, bq = flat & 7;
            union { short8 v; unsigned short h[8]; } o;
#pragma unroll
            for (int j = 0; j < 8; ++j) o.h[j] = f2bf(Ts[(bq * 8 + j) * 65 + rl]);
            *(short8*)(xT + (size_t)(kt * 64 + rl) * 256 + bg * 64 + bq * 8) = o.v;
        }
        // xB[b][k] (row-major bf16, padded)
#pragma unroll
        for (int r = 0; r < 2; ++r) {
            const int flat = r * 256 + tid;  // 512 granules
            const int b = flat >> 3, g = flat & 7;
            union { short8 v; unsigned short h[8]; } o;
#pragma unroll
            for (int j = 0; j < 8; ++j) o.h[j] = f2bf(Ts[b * 65 + g * 8 + j]);
            *(short8*)(xB + (size_t)(bg * 64 + b) * KP + (size_t)kt * 64 + g * 8) = o.v;
        }
    } else {
        __shared__ float Ws[8 * 1032];
        const int i0 = (blockIdx.x - 1204) * 8;
#pragma unroll
        for (int r = 0; r < 8; ++r) {
            const int flat = r * 256 + tid;  // 2048 float4s
            const int g = flat >> 8, rem = flat & 255;
            int gi = i0 + g; if (gi > 2400) gi = 2400;
            const float4 v = *(const float4*)(W + (size_t)gi * 1024 + rem * 4);
            *(float4*)&Ws[g * 1032 + rem * 4] = v;
        }
        __syncthreads();
#pragma unroll
        for (int r = 0; r < 4; ++r) {
            const int flat = r * 256 + tid;  // 1024 granules
            const int oc = flat >> 3, g = flat & 7;
            const int gi = i0 + g;
            union { short8 v; unsigned short h[8]; } w, c;
            if (gi <= 2400) {
                const float* wp = &Ws[g * 1032 + oc * 8];
#pragma unroll
                for (int j = 0; j < 8; ++j) {
                    w.h[j] = f2bf(wp[j]);
                    c.h[j] = f2bf(0.125f * wp[j]);
                }
            } else {
#pragma unroll
                for (int j = 0; j < 8; ++j) { w.h[j] = 0; c.h[j] = 0; }
            }
            *(short8*)(Wbf + (size_t)oc * KP + (size_t)gi * 8) = w.v;
            *(short8*)(cwt + (size_t)oc * KP + (size_t)gi * 8) = c.v;
        }
    }
}

// ---------------- lightweight grid barrier (agent scope, hand-rolled, NOT cg::sync)
__device__ __forceinline__ void gbar(unsigned* bar, unsigned phase, int tid)
{
    __syncthreads();
    if (tid == 0) {
        __threadfence();                                   // release: wb dirty lines
        __hip_atomic_fetch_add(bar, 1u, __ATOMIC_RELEASE, __HIP_MEMORY_SCOPE_AGENT);
        while (__hip_atomic_load(bar, __ATOMIC_ACQUIRE, __HIP_MEMORY_SCOPE_AGENT)
               < (unsigned)NBLK * phase)
            __builtin_amdgcn_s_sleep(4);
        __threadfence();                                   // acquire: inv stale lines
    }
    __syncthreads();
}

// ---------------- S phase: spart[iy][b][oc] = sum_k xB[b,k]*cwt[oc,k]
// bid: bg = bid&3 (64 b-rows), iy = bid>>2 (split-K slice). Reg double-buffer.
__device__ __forceinline__ void s_phase(char* smraw, const int tid, const int bid,
        const unsigned short* __restrict__ xB, const unsigned short* __restrict__ cwt,
        float* __restrict__ spart)
{
    unsigned short* Xs = (unsigned short*)smraw;            // 8 KB
    unsigned short* Bs = (unsigned short*)(smraw + 8192);   // 16 KB
    const int bg = bid & 3, iy = bid >> 2;
    const int b0 = bg * 64;
    const int ln = tid & 63;
    const int mr = ln & 15, qd = ln >> 4;
    const int mh = (tid >> 6) & 1;        // m-half (32 b-rows)
    const int nh = tid >> 7;              // n-half (64 oc)

    f32x4 acc[2][4];
#pragma unroll
    for (int a = 0; a < 2; ++a)
#pragma unroll
        for (int b = 0; b < 4; ++b) acc[a][b] = (f32x4){0.f, 0.f, 0.f, 0.f};

    const int srow = tid >> 3, scol = tid & 7;
    const int ssw  = (scol ^ (srow & 7)) * 8;
    const unsigned short* xp0 = xB  + (size_t)(b0 + srow) * KP + (size_t)scol * 8;
    const unsigned short* bp0 = cwt + (size_t)srow * KP + (size_t)scol * 8;

    short8 vx[2], vb[4];
    int kt = iy;
#pragma unroll
    for (int r = 0; r < 2; ++r) vx[r] = *(const short8*)(xp0 + (size_t)r * 32 * KP + (size_t)kt * 64);
#pragma unroll
    for (int r = 0; r < 4; ++r) vb[r] = *(const short8*)(bp0 + (size_t)r * 32 * KP + (size_t)kt * 64);

    while (true) {
        __syncthreads();
#pragma unroll
        for (int r = 0; r < 2; ++r) *(short8*)&Xs[(r * 32 + srow) * 64 + ssw] = vx[r];
#pragma unroll
        for (int r = 0; r < 4; ++r) *(short8*)&Bs[(r * 32 + srow) * 64 + ssw] = vb[r];
        const int ktn = kt + NI;
        if (ktn < KTILES) {
#pragma unroll
            for (int r = 0; r < 2; ++r) vx[r] = *(const short8*)(xp0 + (size_t)r * 32 * KP + (size_t)ktn * 64);
#pragma unroll
            for (int r = 0; r < 4; ++r) vb[r] = *(const short8*)(bp0 + (size_t)r * 32 * KP + (size_t)ktn * 64);
        }
        __syncthreads();
#pragma unroll
        for (int kk = 0; kk < 2; ++kk) {
            const int csw = ((kk * 4 + qd) ^ (mr & 7)) * 8;
            const short8 a0 = *(const short8*)&Xs[(mh * 32 + mr) * 64 + csw];
            const short8 a1 = *(const short8*)&Xs[(mh * 32 + 16 + mr) * 64 + csw];
#pragma unroll
            for (int nt = 0; nt < 4; ++nt) {
                const short8 b = *(const short8*)&Bs[(nh * 64 + nt * 16 + mr) * 64 + csw];
                acc[0][nt] = __builtin_amdgcn_mfma_f32_16x16x32_bf16(a0, b, acc[0][nt], 0, 0, 0);
                acc[1][nt] = __builtin_amdgcn_mfma_f32_16x16x32_bf16(a1, b, acc[1][nt], 0, 0, 0);
            }
        }
        if (ktn >= KTILES) break;
        kt = ktn;
    }

    float* op = spart + ((size_t)iy * BSZ + b0) * OCC;
#pragma unroll
    for (int mt = 0; mt < 2; ++mt)
#pragma unroll
        for (int nt = 0; nt < 4; ++nt)
#pragma unroll
            for (int r = 0; r < 4; ++r)
                op[(size_t)(mh * 32 + mt * 16 + qd * 4 + r) * OCC + nh * 64 + nt * 16 + mr]
                    = acc[mt][nt][r];
}

// ---------------- Q phase: reduce NI split-K partials + squash. bid*4 rows (row = b*8+o).
__device__ __forceinline__ void q_phase(char* smraw, const int tid, const int bid, const int writeT,
        const float* __restrict__ spart, float* __restrict__ vout, unsigned short* __restrict__ vT)
{
    float* red = (float*)smraw;
    const int r0  = bid * 4;                 // first of 4 rows
    const int idx = tid & 63;                // element within 4x16 chunk
    const int kq  = tid >> 6;                // 4-way k split

    const float* base = spart + (size_t)r0 * 16 + idx;
    float acc = 0.0f;
#pragma unroll 8
    for (int k = kq; k < NI; k += 4) acc += base[(size_t)k * (BSZ * OCC)];
    red[tid] = acc;
    __syncthreads();

    if (tid < 64) {
        const float s = red[tid] + red[tid + 64] + red[tid + 128] + red[tid + 192];
        float ms = s * s;
        ms += __shfl_xor(ms, 1); ms += __shfl_xor(ms, 2);
        ms += __shfl_xor(ms, 4); ms += __shfl_xor(ms, 8);
        const float scale = sqrtf(ms) / (1.0f + ms);   // == mag_sq/(1+mag_sq)/mag
        const float outv = s * scale;
        const int row = r0 + (tid >> 4);     // = b*8 + o
        const int j   = tid & 15;
        if (writeT) {
            vT[(size_t)((row & 7) * 16 + j) * 256 + (row >> 3)] = f2bf(outv);
        } else {
            vout[(size_t)row * 16 + j] = outv;
        }
    }
}

// ---------------- A phase: agreement (MFMA) + bij + softmax + write cwt. t = i-tile.
__device__ __forceinline__ void a_phase(char* smraw, const int tid, const int t, const int first,
        const unsigned short* __restrict__ xT, const unsigned short* __restrict__ vT,
        const unsigned short* __restrict__ Wbf, float* __restrict__ bij,
        unsigned short* __restrict__ cwt)
{
    unsigned short* As = (unsigned short*)smraw;            // [128 oc][64 b]
    unsigned short* Bx = (unsigned short*)(smraw + 16384);  // [64 (i,d)][64 b]
    float* Hs = (float*)smraw;                              // [128][68]

    const int i0  = t * 8;
    const int ln  = tid & 63, wv = tid >> 6;
    const int mr  = ln & 15, qd = ln >> 4;

    f32x4 acc[2][4];
#pragma unroll
    for (int a = 0; a < 2; ++a)
#pragma unroll
        for (int b = 0; b < 4; ++b) acc[a][b] = (f32x4){0.f, 0.f, 0.f, 0.f};

    const int srow = tid >> 3, scol = tid & 7;
    const int ssw  = (scol ^ (srow & 7)) * 8;
    const unsigned short* ap0 = vT + (size_t)srow * 256 + (size_t)scol * 8;
    const unsigned short* bp0 = xT + (size_t)(i0 * 8 + srow) * 256 + (size_t)scol * 8;

    short8 va[4], vbx[2];
#pragma unroll
    for (int r = 0; r < 4; ++r) va[r]  = *(const short8*)(ap0 + (size_t)r * 32 * 256);
#pragma unroll
    for (int r = 0; r < 2; ++r) vbx[r] = *(const short8*)(bp0 + (size_t)r * 32 * 256);

    for (int bc = 0; bc < 4; ++bc) {
        __syncthreads();
#pragma unroll
        for (int r = 0; r < 4; ++r) *(short8*)&As[(r * 32 + srow) * 64 + ssw] = va[r];
#pragma unroll
        for (int r = 0; r < 2; ++r) *(short8*)&Bx[(r * 32 + srow) * 64 + ssw] = vbx[r];
        if (bc < 3) {
#pragma unroll
            for (int r = 0; r < 4; ++r) va[r]  = *(const short8*)(ap0 + (size_t)r * 32 * 256 + (bc + 1) * 64);
#pragma unroll
            for (int r = 0; r < 2; ++r) vbx[r] = *(const short8*)(bp0 + (size_t)r * 32 * 256 + (bc + 1) * 64);
        }
        __syncthreads();
#pragma unroll
        for (int kk = 0; kk < 2; ++kk) {
            const int csw = ((kk * 4 + qd) ^ (mr & 7)) * 8;
#pragma unroll
            for (int nt = 0; nt < 4; ++nt) {
                const short8 b = *(const short8*)&Bx[(nt * 16 + mr) * 64 + csw];
#pragma unroll
                for (int mt = 0; mt < 2; ++mt) {
                    const short8 a = *(const short8*)&As[((wv * 2 + mt) * 16 + mr) * 64 + csw];
                    acc[mt][nt] = __builtin_amdgcn_mfma_f32_16x16x32_bf16(a, b, acc[mt][nt], 0, 0, 0);
                }
            }
        }
    }

    __syncthreads();
#pragma unroll
    for (int mt = 0; mt < 2; ++mt)
#pragma unroll
        for (int nt = 0; nt < 4; ++nt)
#pragma unroll
            for (int r = 0; r < 4; ++r)
                Hs[((wv * 2 + mt) * 16 + qd * 4 + r) * 68 + nt * 16 + mr] = acc[mt][nt][r];
    __syncthreads();

    // phase 2: tid = il*32 + oo*4 + ch
    const int ch = tid & 3, oo = (tid >> 2) & 7, il = tid >> 5;
    const int ival = i0 + il;
    const int gi = (ival < IC) ? ival : IC - 1;
    const unsigned short* Wt = Wbf + (size_t)(oo * 16 + ch * 4) * KP + (size_t)gi * 8;

    float wreg[4][8];
#pragma unroll
    for (int c = 0; c < 4; ++c) {
        union { short8 v; unsigned short h[8]; } uw;
        uw.v = *(const short8*)(Wt + (size_t)c * KP);
#pragma unroll
        for (int j = 0; j < 8; ++j) wreg[c][j] = bf2f(uw.h[j]);
    }
    float p = 0.0f;
#pragma unroll
    for (int c = 0; c < 4; ++c) {
        const float* hr = &Hs[(oo * 16 + ch * 4 + c) * 68 + il * 8];
        const float4 h0 = *(const float4*)hr;
        const float4 h1 = *(const float4*)(hr + 4);
        p = fmaf(wreg[c][0], h0.x, p); p = fmaf(wreg[c][1], h0.y, p);
        p = fmaf(wreg[c][2], h0.z, p); p = fmaf(wreg[c][3], h0.w, p);
        p = fmaf(wreg[c][4], h1.x, p); p = fmaf(wreg[c][5], h1.y, p);
        p = fmaf(wreg[c][6], h1.z, p); p = fmaf(wreg[c][7], h1.w, p);
    }
    p += __shfl_xor(p, 1); p += __shfl_xor(p, 2);   // combine ch quarters
    const float anew = p * (1.0f / 256.0f);
    float bv = anew;
    if (!first) bv += bij[gi * 8 + oo];
    float mx = bv;                                   // softmax over oo (bits 2..4)
    mx = fmaxf(mx, __shfl_xor(mx, 4));
    mx = fmaxf(mx, __shfl_xor(mx, 8));
    mx = fmaxf(mx, __shfl_xor(mx, 16));
    const float e = expf(bv - mx);
    float ss = e;
    ss += __shfl_xor(ss, 4); ss += __shfl_xor(ss, 8); ss += __shfl_xor(ss, 16);
    float cv = e / ss;
    if (ival >= IC) cv = 0.0f;                       // keep cwt pad rows zero
    if (ch == 0 && ival < IC) bij[ival * 8 + oo] = bv;
#pragma unroll
    for (int c = 0; c < 4; ++c) {
        union { short8 v; unsigned short h[8]; } o;
#pragma unroll
        for (int j = 0; j < 8; ++j) o.h[j] = f2bf(cv * wreg[c][j]);
        *(short8*)(cwt + (size_t)(oo * 16 + ch * 4 + c) * KP + (size_t)ival * 8) = o.v;
    }
}

// ---------------- persistent fused routing kernel: 7 hand-rolled grid barriers, 1 launch.
__global__ __launch_bounds__(256, 2)
void routing_kernel(const unsigned short* __restrict__ xT,
                    const unsigned short* __restrict__ xB,
                    const unsigned short* __restrict__ Wbf,
                    unsigned short* __restrict__ cwt,
                    float* __restrict__ spart,
                    unsigned short* __restrict__ vT,
                    float* __restrict__ bij,
                    float* __restrict__ out,
                    unsigned* __restrict__ bar)
{
    __shared__ __align__(16) char sm[128 * 68 * 4];   // 34816 B, reused per phase
    const int tid = threadIdx.x;
    const int bid = blockIdx.x;
    unsigned phase = 0;

#pragma unroll 1
    for (int iter = 0; iter < 3; ++iter) {
        s_phase(sm, tid, bid, xB, cwt, spart);
        gbar(bar, ++phase, tid);
        q_phase(sm, tid, bid, (iter < 2) ? 1 : 0, spart, out, vT);
        if (iter == 2) return;
        gbar(bar, ++phase, tid);
        if (bid < KTILES) a_phase(sm, tid, bid, (iter == 0) ? 1 : 0, xT, vT, Wbf, bij, cwt);
        gbar(bar, ++phase, tid);
    }
}

// ---------------- classic-launch fallback wrappers (same device bodies)
__global__ __launch_bounds__(256, 2)
void s_gemm_k(const unsigned short* __restrict__ xB, const unsigned short* __restrict__ cwt,
              float* __restrict__ spart)
{
    __shared__ __align__(16) char sm[24576];
    s_phase(sm, threadIdx.x, blockIdx.x, xB, cwt, spart);
}

__global__ __launch_bounds__(256)
void squash_k(const float* __restrict__ spart, float* __restrict__ vout,
              unsigned short* __restrict__ vT, int writeT)
{
    __shared__ __align__(16) char sm[1024];
    q_phase(sm, threadIdx.x, blockIdx.x, writeT, spart, vout, vT);
}

__global__ __launch_bounds__(256, 2)
void a_gemm_k(const unsigned short* __restrict__ xT, const unsigned short* __restrict__ vT,
              const unsigned short* __restrict__ Wbf, float* __restrict__ bij,
              unsigned short* __restrict__ cwt, int first)
{
    __shared__ __align__(16) char sm[34816];
    a_phase(sm, threadIdx.x, blockIdx.x, first, xT, vT, Wbf, bij, cwt);
}

extern "C" void kernel_launch(void* const* d_in, const int* in_sizes, int n_in,
                              void* d_out, int out_size, void* d_ws, size_t ws_size,
                              hipStream_t stream)
{
    const float* x = (const float*)d_in[0];   // [256, 2401, 8]
    const float* W = (const float*)d_in[1];   // [2401, 8, 16, 8]
    float* out = (float*)d_out;               // [256, 8, 16]

    char* p = (char*)d_ws;
    float*          spart = (float*)p;          p += (size_t)NI * BSZ * OCC * 4;   // 16.8 MB
    unsigned short* xT    = (unsigned short*)p; p += (size_t)KP * 256 * 2;         // 9.86 MB
    unsigned short* xB    = (unsigned short*)p; p += (size_t)256 * KP * 2;         // 9.86 MB
    unsigned short* Wbf   = (unsigned short*)p; p += (size_t)128 * KP * 2;         // 4.93 MB
    unsigned short* cwt   = (unsigned short*)p; p += (size_t)128 * KP * 2;         // 4.93 MB
    unsigned short* vT    = (unsigned short*)p; p += (size_t)128 * 256 * 2;        // 64 KB
    float*          bij   = (float*)p;          p += 81920;                        // 77 KB + pad
    unsigned*       bar   = (unsigned*)p;

    prep_kernel<<<1505, 256, 0, stream>>>(x, W, xT, xB, Wbf, cwt, bar);

    void* kargs[] = { (void*)&xT, (void*)&xB, (void*)&Wbf, (void*)&cwt,
                      (void*)&spart, (void*)&vT, (void*)&bij, (void*)&out, (void*)&bar };
    hipError_t err = hipLaunchCooperativeKernel((void*)routing_kernel,
                                                dim3(NBLK), dim3(256), kargs, 0, stream);
    if (err != hipSuccess) {
        // fallback: classic 8-launch pipeline (identical math)
        s_gemm_k<<<NBLK, 256, 0, stream>>>(xB, cwt, spart);
        squash_k<<<NBLK, 256, 0, stream>>>(spart, nullptr, vT, 1);
        a_gemm_k<<<KTILES, 256, 0, stream>>>(xT, vT, Wbf, bij, cwt, 1);
        s_gemm_k<<<NBLK, 256, 0, stream>>>(xB, cwt, spart);
        squash_k<<<NBLK, 256, 0, stream>>>(spart, nullptr, vT, 1);
        a_gemm_k<<<KTILES, 256, 0, stream>>>(xT, vT, Wbf, bij, cwt, 0);
        s_gemm_k<<<NBLK, 256, 0, stream>>>(xB, cwt, spart);
        squash_k<<<NBLK, 256, 0, stream>>>(spart, out, vT, 0);
    }
}

// Round 4
// 424.589 us; speedup vs baseline: 1.6178x; 1.6178x over previous
//
#include <hip/hip_runtime.h>
#include <math.h>

#define IC     2401
#define BSZ    256
#define OC     8
#define CS     16
#define OCC    128     // OC*CS
#define XROW   19208   // x row length (floats) = IC*8
#define KP     19264   // padded K (=301*64 = 2408 granules of 8), pad zeroed
#define KTILES 301
#define NI     128     // split-K slices for s phase
#define NBLK   512     // persistent grid: 4 bg * NI, 2 blocks/CU

typedef __attribute__((ext_vector_type(8))) short short8;
typedef __attribute__((ext_vector_type(4))) float f32x4;

__device__ __forceinline__ unsigned short f2bf(float f) {
    union { float f; unsigned u; } v; v.f = f;
    const unsigned r = v.u + 0x7FFF + ((v.u >> 16) & 1);   // RNE
    return (unsigned short)(r >> 16);
}
__device__ __forceinline__ float bf2f(unsigned short h) {
    union { unsigned u; float f; } v; v.u = ((unsigned)h) << 16;
    return v.f;
}

// ---------------- prep (one launch): blocks 0..1203 -> xT + xB ; 1204..1504 -> Wbf + cwt0
__global__ __launch_bounds__(256)
void prep_kernel(const float* __restrict__ x, const float* __restrict__ W,
                 unsigned short* __restrict__ xT, unsigned short* __restrict__ xB,
                 unsigned short* __restrict__ Wbf, unsigned short* __restrict__ cwt,
                 unsigned* __restrict__ bar)
{
    const int tid = threadIdx.x;
    if (blockIdx.x == 0 && tid == 0) *bar = 0;   // reset grid-barrier counter each replay
    if (blockIdx.x < 1204) {
        __shared__ float Ts[64 * 65];
        const int bg = blockIdx.x & 3;       // b-group of 64
        const int kt = blockIdx.x >> 2;      // k-tile 0..300
#pragma unroll
        for (int r = 0; r < 4; ++r) {
            const int flat = r * 256 + tid;  // 1024 float4s
            const int b = flat >> 4, cq = flat & 15;
            const int col = kt * 64 + cq * 4;
            float4 v = make_float4(0.f, 0.f, 0.f, 0.f);
            if (col < XROW) v = *(const float4*)(x + (size_t)(bg * 64 + b) * XROW + col);
            *(float4*)&Ts[b * 65 + cq * 4] = v;
        }
        __syncthreads();
        // xT[k][b] (transposed)
#pragma unroll
        for (int r = 0; r < 2; ++r) {
            const int flat = r * 256 + tid;  // 512 granules
            const int rl = flat >> 3, bq = flat & 7;
            union { short8 v; unsigned short h[8]; } o;
#pragma unroll
            for (int j = 0; j < 8; ++j) o.h[j] = f2bf(Ts[(bq * 8 + j) * 65 + rl]);
            *(short8*)(xT + (size_t)(kt * 64 + rl) * 256 + bg * 64 + bq * 8) = o.v;
        }
        // xB[b][k] (row-major bf16, padded)
#pragma unroll
        for (int r = 0; r < 2; ++r) {
            const int flat = r * 256 + tid;  // 512 granules
            const int b = flat >> 3, g = flat & 7;
            union { short8 v; unsigned short h[8]; } o;
#pragma unroll
            for (int j = 0; j < 8; ++j) o.h[j] = f2bf(Ts[b * 65 + g * 8 + j]);
            *(short8*)(xB + (size_t)(bg * 64 + b) * KP + (size_t)kt * 64 + g * 8) = o.v;
        }
    } else {
        __shared__ float Ws[8 * 1032];
        const int i0 = (blockIdx.x - 1204) * 8;
#pragma unroll
        for (int r = 0; r < 8; ++r) {
            const int flat = r * 256 + tid;  // 2048 float4s
            const int g = flat >> 8, rem = flat & 255;
            int gi = i0 + g; if (gi > 2400) gi = 2400;
            const float4 v = *(const float4*)(W + (size_t)gi * 1024 + rem * 4);
            *(float4*)&Ws[g * 1032 + rem * 4] = v;
        }
        __syncthreads();
#pragma unroll
        for (int r = 0; r < 4; ++r) {
            const int flat = r * 256 + tid;  // 1024 granules
            const int oc = flat >> 3, g = flat & 7;
            const int gi = i0 + g;
            union { short8 v; unsigned short h[8]; } w, c;
            if (gi <= 2400) {
                const float* wp = &Ws[g * 1032 + oc * 8];
#pragma unroll
                for (int j = 0; j < 8; ++j) {
                    w.h[j] = f2bf(wp[j]);
                    c.h[j] = f2bf(0.125f * wp[j]);
                }
            } else {
#pragma unroll
                for (int j = 0; j < 8; ++j) { w.h[j] = 0; c.h[j] = 0; }
            }
            *(short8*)(Wbf + (size_t)oc * KP + (size_t)gi * 8) = w.v;
            *(short8*)(cwt + (size_t)oc * KP + (size_t)gi * 8) = c.v;
        }
    }
}

// ---------------- grid barrier v2: RELAXED polls (no per-poll buffer_inv),
// exactly one release fence (wbL2) before arrival, one acquire fence (inv) after pass.
__device__ __forceinline__ void gbar(unsigned* bar, unsigned target, int tid)
{
    __syncthreads();
    if (tid == 0) {
        __builtin_amdgcn_fence(__ATOMIC_RELEASE, "agent");   // wb dirty lines once
        __hip_atomic_fetch_add(bar, 1u, __ATOMIC_RELAXED, __HIP_MEMORY_SCOPE_AGENT);
        int spins = 0;
        while (__hip_atomic_load(bar, __ATOMIC_RELAXED, __HIP_MEMORY_SCOPE_AGENT) < target) {
            __builtin_amdgcn_s_sleep(2);
            if (++spins == 65536) {                          // livelock safety valve
                __builtin_amdgcn_fence(__ATOMIC_ACQUIRE, "agent");
                spins = 0;
            }
        }
        __builtin_amdgcn_fence(__ATOMIC_ACQUIRE, "agent");   // inv stale lines once
    }
    __syncthreads();
}

// ---------------- S phase: spart[iy][b][oc] = sum_k xB[b,k]*cwt[oc,k]
// bid: bg = bid&3 (64 b-rows), iy = bid>>2 (split-K slice). Reg double-buffer.
__device__ __forceinline__ void s_phase(char* smraw, const int tid, const int bid,
        const unsigned short* __restrict__ xB, const unsigned short* __restrict__ cwt,
        float* __restrict__ spart)
{
    unsigned short* Xs = (unsigned short*)smraw;            // 8 KB
    unsigned short* Bs = (unsigned short*)(smraw + 8192);   // 16 KB
    const int bg = bid & 3, iy = bid >> 2;
    const int b0 = bg * 64;
    const int ln = tid & 63;
    const int mr = ln & 15, qd = ln >> 4;
    const int mh = (tid >> 6) & 1;        // m-half (32 b-rows)
    const int nh = tid >> 7;              // n-half (64 oc)

    f32x4 acc[2][4];
#pragma unroll
    for (int a = 0; a < 2; ++a)
#pragma unroll
        for (int b = 0; b < 4; ++b) acc[a][b] = (f32x4){0.f, 0.f, 0.f, 0.f};

    const int srow = tid >> 3, scol = tid & 7;
    const int ssw  = (scol ^ (srow & 7)) * 8;
    const unsigned short* xp0 = xB  + (size_t)(b0 + srow) * KP + (size_t)scol * 8;
    const unsigned short* bp0 = cwt + (size_t)srow * KP + (size_t)scol * 8;

    short8 vx[2], vb[4];
    int kt = iy;
#pragma unroll
    for (int r = 0; r < 2; ++r) vx[r] = *(const short8*)(xp0 + (size_t)r * 32 * KP + (size_t)kt * 64);
#pragma unroll
    for (int r = 0; r < 4; ++r) vb[r] = *(const short8*)(bp0 + (size_t)r * 32 * KP + (size_t)kt * 64);

    while (true) {
        __syncthreads();
#pragma unroll
        for (int r = 0; r < 2; ++r) *(short8*)&Xs[(r * 32 + srow) * 64 + ssw] = vx[r];
#pragma unroll
        for (int r = 0; r < 4; ++r) *(short8*)&Bs[(r * 32 + srow) * 64 + ssw] = vb[r];
        const int ktn = kt + NI;
        if (ktn < KTILES) {
#pragma unroll
            for (int r = 0; r < 2; ++r) vx[r] = *(const short8*)(xp0 + (size_t)r * 32 * KP + (size_t)ktn * 64);
#pragma unroll
            for (int r = 0; r < 4; ++r) vb[r] = *(const short8*)(bp0 + (size_t)r * 32 * KP + (size_t)ktn * 64);
        }
        __syncthreads();
#pragma unroll
        for (int kk = 0; kk < 2; ++kk) {
            const int csw = ((kk * 4 + qd) ^ (mr & 7)) * 8;
            const short8 a0 = *(const short8*)&Xs[(mh * 32 + mr) * 64 + csw];
            const short8 a1 = *(const short8*)&Xs[(mh * 32 + 16 + mr) * 64 + csw];
#pragma unroll
            for (int nt = 0; nt < 4; ++nt) {
                const short8 b = *(const short8*)&Bs[(nh * 64 + nt * 16 + mr) * 64 + csw];
                acc[0][nt] = __builtin_amdgcn_mfma_f32_16x16x32_bf16(a0, b, acc[0][nt], 0, 0, 0);
                acc[1][nt] = __builtin_amdgcn_mfma_f32_16x16x32_bf16(a1, b, acc[1][nt], 0, 0, 0);
            }
        }
        if (ktn >= KTILES) break;
        kt = ktn;
    }

    float* op = spart + ((size_t)iy * BSZ + b0) * OCC;
#pragma unroll
    for (int mt = 0; mt < 2; ++mt)
#pragma unroll
        for (int nt = 0; nt < 4; ++nt)
#pragma unroll
            for (int r = 0; r < 4; ++r)
                op[(size_t)(mh * 32 + mt * 16 + qd * 4 + r) * OCC + nh * 64 + nt * 16 + mr]
                    = acc[mt][nt][r];
}

// ---------------- Q phase: reduce NI split-K partials + squash. bid*4 rows (row = b*8+o).
__device__ __forceinline__ void q_phase(char* smraw, const int tid, const int bid, const int writeT,
        const float* __restrict__ spart, float* __restrict__ vout, unsigned short* __restrict__ vT)
{
    float* red = (float*)smraw;
    const int r0  = bid * 4;                 // first of 4 rows
    const int idx = tid & 63;                // element within 4x16 chunk
    const int kq  = tid >> 6;                // 4-way k split

    const float* base = spart + (size_t)r0 * 16 + idx;
    float acc = 0.0f;
#pragma unroll 8
    for (int k = kq; k < NI; k += 4) acc += base[(size_t)k * (BSZ * OCC)];
    red[tid] = acc;
    __syncthreads();

    if (tid < 64) {
        const float s = red[tid] + red[tid + 64] + red[tid + 128] + red[tid + 192];
        float ms = s * s;
        ms += __shfl_xor(ms, 1); ms += __shfl_xor(ms, 2);
        ms += __shfl_xor(ms, 4); ms += __shfl_xor(ms, 8);
        const float scale = sqrtf(ms) / (1.0f + ms);   // == mag_sq/(1+mag_sq)/mag
        const float outv = s * scale;
        const int row = r0 + (tid >> 4);     // = b*8 + o
        const int j   = tid & 15;
        if (writeT) {
            vT[(size_t)((row & 7) * 16 + j) * 256 + (row >> 3)] = f2bf(outv);
        } else {
            vout[(size_t)row * 16 + j] = outv;
        }
    }
}

// ---------------- A phase: agreement (MFMA) + bij + softmax + write cwt. t = i-tile.
__device__ __forceinline__ void a_phase(char* smraw, const int tid, const int t, const int first,
        const unsigned short* __restrict__ xT, const unsigned short* __restrict__ vT,
        const unsigned short* __restrict__ Wbf, float* __restrict__ bij,
        unsigned short* __restrict__ cwt)
{
    unsigned short* As = (unsigned short*)smraw;            // [128 oc][64 b]
    unsigned short* Bx = (unsigned short*)(smraw + 16384);  // [64 (i,d)][64 b]
    float* Hs = (float*)smraw;                              // [128][68]

    const int i0  = t * 8;
    const int ln  = tid & 63, wv = tid >> 6;
    const int mr  = ln & 15, qd = ln >> 4;

    f32x4 acc[2][4];
#pragma unroll
    for (int a = 0; a < 2; ++a)
#pragma unroll
        for (int b = 0; b < 4; ++b) acc[a][b] = (f32x4){0.f, 0.f, 0.f, 0.f};

    const int srow = tid >> 3, scol = tid & 7;
    const int ssw  = (scol ^ (srow & 7)) * 8;
    const unsigned short* ap0 = vT + (size_t)srow * 256 + (size_t)scol * 8;
    const unsigned short* bp0 = xT + (size_t)(i0 * 8 + srow) * 256 + (size_t)scol * 8;

    short8 va[4], vbx[2];
#pragma unroll
    for (int r = 0; r < 4; ++r) va[r]  = *(const short8*)(ap0 + (size_t)r * 32 * 256);
#pragma unroll
    for (int r = 0; r < 2; ++r) vbx[r] = *(const short8*)(bp0 + (size_t)r * 32 * 256);

    for (int bc = 0; bc < 4; ++bc) {
        __syncthreads();
#pragma unroll
        for (int r = 0; r < 4; ++r) *(short8*)&As[(r * 32 + srow) * 64 + ssw] = va[r];
#pragma unroll
        for (int r = 0; r < 2; ++r) *(short8*)&Bx[(r * 32 + srow) * 64 + ssw] = vbx[r];
        if (bc < 3) {
#pragma unroll
            for (int r = 0; r < 4; ++r) va[r]  = *(const short8*)(ap0 + (size_t)r * 32 * 256 + (bc + 1) * 64);
#pragma unroll
            for (int r = 0; r < 2; ++r) vbx[r] = *(const short8*)(bp0 + (size_t)r * 32 * 256 + (bc + 1) * 64);
        }
        __syncthreads();
#pragma unroll
        for (int kk = 0; kk < 2; ++kk) {
            const int csw = ((kk * 4 + qd) ^ (mr & 7)) * 8;
#pragma unroll
            for (int nt = 0; nt < 4; ++nt) {
                const short8 b = *(const short8*)&Bx[(nt * 16 + mr) * 64 + csw];
#pragma unroll
                for (int mt = 0; mt < 2; ++mt) {
                    const short8 a = *(const short8*)&As[((wv * 2 + mt) * 16 + mr) * 64 + csw];
                    acc[mt][nt] = __builtin_amdgcn_mfma_f32_16x16x32_bf16(a, b, acc[mt][nt], 0, 0, 0);
                }
            }
        }
    }

    __syncthreads();
#pragma unroll
    for (int mt = 0; mt < 2; ++mt)
#pragma unroll
        for (int nt = 0; nt < 4; ++nt)
#pragma unroll
            for (int r = 0; r < 4; ++r)
                Hs[((wv * 2 + mt) * 16 + qd * 4 + r) * 68 + nt * 16 + mr] = acc[mt][nt][r];
    __syncthreads();

    // phase 2: tid = il*32 + oo*4 + ch
    const int ch = tid & 3, oo = (tid >> 2) & 7, il = tid >> 5;
    const int ival = i0 + il;
    const int gi = (ival < IC) ? ival : IC - 1;
    const unsigned short* Wt = Wbf + (size_t)(oo * 16 + ch * 4) * KP + (size_t)gi * 8;

    float wreg[4][8];
#pragma unroll
    for (int c = 0; c < 4; ++c) {
        union { short8 v; unsigned short h[8]; } uw;
        uw.v = *(const short8*)(Wt + (size_t)c * KP);
#pragma unroll
        for (int j = 0; j < 8; ++j) wreg[c][j] = bf2f(uw.h[j]);
    }
    float p = 0.0f;
#pragma unroll
    for (int c = 0; c < 4; ++c) {
        const float* hr = &Hs[(oo * 16 + ch * 4 + c) * 68 + il * 8];
        const float4 h0 = *(const float4*)hr;
        const float4 h1 = *(const float4*)(hr + 4);
        p = fmaf(wreg[c][0], h0.x, p); p = fmaf(wreg[c][1], h0.y, p);
        p = fmaf(wreg[c][2], h0.z, p); p = fmaf(wreg[c][3], h0.w, p);
        p = fmaf(wreg[c][4], h1.x, p); p = fmaf(wreg[c][5], h1.y, p);
        p = fmaf(wreg[c][6], h1.z, p); p = fmaf(wreg[c][7], h1.w, p);
    }
    p += __shfl_xor(p, 1); p += __shfl_xor(p, 2);   // combine ch quarters
    const float anew = p * (1.0f / 256.0f);
    float bv = anew;
    if (!first) bv += bij[gi * 8 + oo];
    float mx = bv;                                   // softmax over oo (bits 2..4)
    mx = fmaxf(mx, __shfl_xor(mx, 4));
    mx = fmaxf(mx, __shfl_xor(mx, 8));
    mx = fmaxf(mx, __shfl_xor(mx, 16));
    const float e = expf(bv - mx);
    float ss = e;
    ss += __shfl_xor(ss, 4); ss += __shfl_xor(ss, 8); ss += __shfl_xor(ss, 16);
    float cv = e / ss;
    if (ival >= IC) cv = 0.0f;                       // keep cwt pad rows zero
    if (ch == 0 && ival < IC) bij[ival * 8 + oo] = bv;
#pragma unroll
    for (int c = 0; c < 4; ++c) {
        union { short8 v; unsigned short h[8]; } o;
#pragma unroll
        for (int j = 0; j < 8; ++j) o.h[j] = f2bf(cv * wreg[c][j]);
        *(short8*)(cwt + (size_t)(oo * 16 + ch * 4 + c) * KP + (size_t)ival * 8) = o.v;
    }
}

// ---------------- persistent fused routing kernel: 7 grid barriers (v2), 1 launch.
__global__ __launch_bounds__(256, 2)
void routing_kernel(const unsigned short* __restrict__ xT,
                    const unsigned short* __restrict__ xB,
                    const unsigned short* __restrict__ Wbf,
                    unsigned short* __restrict__ cwt,
                    float* __restrict__ spart,
                    unsigned short* __restrict__ vT,
                    float* __restrict__ bij,
                    float* __restrict__ out,
                    unsigned* __restrict__ bar)
{
    __shared__ __align__(16) char sm[128 * 68 * 4];   // 34816 B, reused per phase
    const int tid = threadIdx.x;
    const int bid = blockIdx.x;
    unsigned phase = 0;

#pragma unroll 1
    for (int iter = 0; iter < 3; ++iter) {
        s_phase(sm, tid, bid, xB, cwt, spart);
        gbar(bar, (unsigned)NBLK * (++phase), tid);
        q_phase(sm, tid, bid, (iter < 2) ? 1 : 0, spart, out, vT);
        if (iter == 2) return;
        gbar(bar, (unsigned)NBLK * (++phase), tid);
        if (bid < KTILES) a_phase(sm, tid, bid, (iter == 0) ? 1 : 0, xT, vT, Wbf, bij, cwt);
        gbar(bar, (unsigned)NBLK * (++phase), tid);
    }
}

// ---------------- classic-launch fallback wrappers (same device bodies)
__global__ __launch_bounds__(256, 2)
void s_gemm_k(const unsigned short* __restrict__ xB, const unsigned short* __restrict__ cwt,
              float* __restrict__ spart)
{
    __shared__ __align__(16) char sm[24576];
    s_phase(sm, threadIdx.x, blockIdx.x, xB, cwt, spart);
}

__global__ __launch_bounds__(256)
void squash_k(const float* __restrict__ spart, float* __restrict__ vout,
              unsigned short* __restrict__ vT, int writeT)
{
    __shared__ __align__(16) char sm[1024];
    q_phase(sm, threadIdx.x, blockIdx.x, writeT, spart, vout, vT);
}

__global__ __launch_bounds__(256, 2)
void a_gemm_k(const unsigned short* __restrict__ xT, const unsigned short* __restrict__ vT,
              const unsigned short* __restrict__ Wbf, float* __restrict__ bij,
              unsigned short* __restrict__ cwt, int first)
{
    __shared__ __align__(16) char sm[34816];
    a_phase(sm, threadIdx.x, blockIdx.x, first, xT, vT, Wbf, bij, cwt);
}

extern "C" void kernel_launch(void* const* d_in, const int* in_sizes, int n_in,
                              void* d_out, int out_size, void* d_ws, size_t ws_size,
                              hipStream_t stream)
{
    const float* x = (const float*)d_in[0];   // [256, 2401, 8]
    const float* W = (const float*)d_in[1];   // [2401, 8, 16, 8]
    float* out = (float*)d_out;               // [256, 8, 16]

    char* p = (char*)d_ws;
    float*          spart = (float*)p;          p += (size_t)NI * BSZ * OCC * 4;   // 16.8 MB
    unsigned short* xT    = (unsigned short*)p; p += (size_t)KP * 256 * 2;         // 9.86 MB
    unsigned short* xB    = (unsigned short*)p; p += (size_t)256 * KP * 2;         // 9.86 MB
    unsigned short* Wbf   = (unsigned short*)p; p += (size_t)128 * KP * 2;         // 4.93 MB
    unsigned short* cwt   = (unsigned short*)p; p += (size_t)128 * KP * 2;         // 4.93 MB
    unsigned short* vT    = (unsigned short*)p; p += (size_t)128 * 256 * 2;        // 64 KB
    float*          bij   = (float*)p;          p += 81920;                        // 77 KB + pad
    unsigned*       bar   = (unsigned*)p;

    prep_kernel<<<1505, 256, 0, stream>>>(x, W, xT, xB, Wbf, cwt, bar);

    void* kargs[] = { (void*)&xT, (void*)&xB, (void*)&Wbf, (void*)&cwt,
                      (void*)&spart, (void*)&vT, (void*)&bij, (void*)&out, (void*)&bar };
    hipError_t err = hipLaunchCooperativeKernel((void*)routing_kernel,
                                                dim3(NBLK), dim3(256), kargs, 0, stream);
    if (err != hipSuccess) {
        // fallback: classic 9-launch pipeline (identical math)
        s_gemm_k<<<NBLK, 256, 0, stream>>>(xB, cwt, spart);
        squash_k<<<NBLK, 256, 0, stream>>>(spart, nullptr, vT, 1);
        a_gemm_k<<<KTILES, 256, 0, stream>>>(xT, vT, Wbf, bij, cwt, 1);
        s_gemm_k<<<NBLK, 256, 0, stream>>>(xB, cwt, spart);
        squash_k<<<NBLK, 256, 0, stream>>>(spart, nullptr, vT, 1);
        a_gemm_k<<<KTILES, 256, 0, stream>>>(xT, vT, Wbf, bij, cwt, 0);
        s_gemm_k<<<NBLK, 256, 0, stream>>>(xB, cwt, spart);
        squash_k<<<NBLK, 256, 0, stream>>>(spart, out, vT, 0);
    }
}

// Round 6
// 138.911 us; speedup vs baseline: 4.9449x; 3.0566x over previous
//
#include <hip/hip_runtime.h>
#include <math.h>

#define IC     2401
#define BSZ    256
#define OC     8
#define CS     16
#define OCC    128     // OC*CS
#define XROW   19208   // x row length (floats) = IC*8
#define KP     19264   // padded K (=301*64 = 2408 granules of 8), pad zeroed
#define KTILES 301
#define SNI    32      // split-K slices for s_gemm (grid 4 x 32 = 128 blocks)

typedef __attribute__((ext_vector_type(8))) short short8;
typedef __attribute__((ext_vector_type(4))) float f32x4;

__device__ __forceinline__ unsigned short f2bf(float f) {
    union { float f; unsigned u; } v; v.f = f;
    const unsigned r = v.u + 0x7FFF + ((v.u >> 16) & 1);   // RNE
    return (unsigned short)(r >> 16);
}
__device__ __forceinline__ float bf2f(unsigned short h) {
    union { unsigned u; float f; } v; v.u = ((unsigned)h) << 16;
    return v.f;
}
__device__ __forceinline__ void atomAddF32(float* p, float v) {
    (void)__hip_atomic_fetch_add(p, v, __ATOMIC_RELAXED, __HIP_MEMORY_SCOPE_AGENT);
}

// ---------------- prep: blocks 0..1203 -> xT + xB ; 1204..1504 -> Wbf + cwt0.
// Blocks 0..2 additionally zero the three s_acc buffers (131 KB each).
__global__ __launch_bounds__(256)
void prep_kernel(const float* __restrict__ x, const float* __restrict__ W,
                 unsigned short* __restrict__ xT, unsigned short* __restrict__ xB,
                 unsigned short* __restrict__ Wbf, unsigned short* __restrict__ cwt,
                 float* __restrict__ s_acc_all)
{
    const int tid = threadIdx.x;
    if (blockIdx.x < 3) {                    // zero s_acc[blockIdx.x] (32768 f32)
        float4* z = (float4*)(s_acc_all + (size_t)blockIdx.x * BSZ * OCC);
#pragma unroll
        for (int r = 0; r < 32; ++r)
            z[r * 256 + tid] = make_float4(0.f, 0.f, 0.f, 0.f);
    }
    if (blockIdx.x < 1204) {
        __shared__ float Ts[64 * 65];
        const int bg = blockIdx.x & 3;       // b-group of 64
        const int kt = blockIdx.x >> 2;      // k-tile 0..300
#pragma unroll
        for (int r = 0; r < 4; ++r) {
            const int flat = r * 256 + tid;  // 1024 float4s
            const int b = flat >> 4, cq = flat & 15;
            const int col = kt * 64 + cq * 4;
            float4 v = make_float4(0.f, 0.f, 0.f, 0.f);
            if (col < XROW) v = *(const float4*)(x + (size_t)(bg * 64 + b) * XROW + col);
            *(float4*)&Ts[b * 65 + cq * 4] = v;
        }
        __syncthreads();
        // xT[k][b] (transposed)
#pragma unroll
        for (int r = 0; r < 2; ++r) {
            const int flat = r * 256 + tid;  // 512 granules
            const int rl = flat >> 3, bq = flat & 7;
            union { short8 v; unsigned short h[8]; } o;
#pragma unroll
            for (int j = 0; j < 8; ++j) o.h[j] = f2bf(Ts[(bq * 8 + j) * 65 + rl]);
            *(short8*)(xT + (size_t)(kt * 64 + rl) * 256 + bg * 64 + bq * 8) = o.v;
        }
        // xB[b][k] (row-major bf16, padded)
#pragma unroll
        for (int r = 0; r < 2; ++r) {
            const int flat = r * 256 + tid;  // 512 granules
            const int b = flat >> 3, g = flat & 7;
            union { short8 v; unsigned short h[8]; } o;
#pragma unroll
            for (int j = 0; j < 8; ++j) o.h[j] = f2bf(Ts[b * 65 + g * 8 + j]);
            *(short8*)(xB + (size_t)(bg * 64 + b) * KP + (size_t)kt * 64 + g * 8) = o.v;
        }
    } else {
        __shared__ float Ws[8 * 1032];
        const int i0 = (blockIdx.x - 1204) * 8;
#pragma unroll
        for (int r = 0; r < 8; ++r) {
            const int flat = r * 256 + tid;  // 2048 float4s
            const int g = flat >> 8, rem = flat & 255;
            int gi = i0 + g; if (gi > 2400) gi = 2400;
            const float4 v = *(const float4*)(W + (size_t)gi * 1024 + rem * 4);
            *(float4*)&Ws[g * 1032 + rem * 4] = v;
        }
        __syncthreads();
#pragma unroll
        for (int r = 0; r < 4; ++r) {
            const int flat = r * 256 + tid;  // 1024 granules
            const int oc = flat >> 3, g = flat & 7;
            const int gi = i0 + g;
            union { short8 v; unsigned short h[8]; } w, c;
            if (gi <= 2400) {
                const float* wp = &Ws[g * 1032 + oc * 8];
#pragma unroll
                for (int j = 0; j < 8; ++j) {
                    w.h[j] = f2bf(wp[j]);
                    c.h[j] = f2bf(0.125f * wp[j]);
                }
            } else {
#pragma unroll
                for (int j = 0; j < 8; ++j) { w.h[j] = 0; c.h[j] = 0; }
            }
            *(short8*)(Wbf + (size_t)oc * KP + (size_t)gi * 8) = w.v;
            *(short8*)(cwt + (size_t)oc * KP + (size_t)gi * 8) = c.v;
        }
    }
}

// ---------------- s: s_acc[b][oc] += sum_k xB[b,k]*cwt[oc,k]  (split-K via HW f32 atomics)
// grid (4 bg, SNI), 256 thr. Block 64b x 128oc; wave 32b x 64oc. Reg double-buffer.
__global__ __launch_bounds__(256, 2)
void s_gemm(const unsigned short* __restrict__ xB, const unsigned short* __restrict__ cwt,
            float* __restrict__ s_acc)
{
    __shared__ __align__(16) unsigned short Xs[64 * 64];    // 8 KB
    __shared__ __align__(16) unsigned short Bs[128 * 64];   // 16 KB
    const int tid = threadIdx.x;
    const int bg  = blockIdx.x, iy = blockIdx.y;
    const int b0  = bg * 64;
    const int ln  = tid & 63;
    const int mr  = ln & 15, qd = ln >> 4;
    const int mh  = (tid >> 6) & 1;        // m-half (32 b-rows)
    const int nh  = tid >> 7;              // n-half (64 oc)

    f32x4 acc[2][4];
#pragma unroll
    for (int a = 0; a < 2; ++a)
#pragma unroll
        for (int b = 0; b < 4; ++b) acc[a][b] = (f32x4){0.f, 0.f, 0.f, 0.f};

    const int srow = tid >> 3, scol = tid & 7;
    const int ssw  = (scol ^ (srow & 7)) * 8;
    const unsigned short* xp0 = xB  + (size_t)(b0 + srow) * KP + (size_t)scol * 8;
    const unsigned short* bp0 = cwt + (size_t)srow * KP + (size_t)scol * 8;

    short8 vx[2], vb[4];
    int kt = iy;
#pragma unroll
    for (int r = 0; r < 2; ++r) vx[r] = *(const short8*)(xp0 + (size_t)r * 32 * KP + (size_t)kt * 64);
#pragma unroll
    for (int r = 0; r < 4; ++r) vb[r] = *(const short8*)(bp0 + (size_t)r * 32 * KP + (size_t)kt * 64);

    while (true) {
        __syncthreads();
#pragma unroll
        for (int r = 0; r < 2; ++r) *(short8*)&Xs[(r * 32 + srow) * 64 + ssw] = vx[r];
#pragma unroll
        for (int r = 0; r < 4; ++r) *(short8*)&Bs[(r * 32 + srow) * 64 + ssw] = vb[r];
        const int ktn = kt + SNI;
        if (ktn < KTILES) {
#pragma unroll
            for (int r = 0; r < 2; ++r) vx[r] = *(const short8*)(xp0 + (size_t)r * 32 * KP + (size_t)ktn * 64);
#pragma unroll
            for (int r = 0; r < 4; ++r) vb[r] = *(const short8*)(bp0 + (size_t)r * 32 * KP + (size_t)ktn * 64);
        }
        __syncthreads();
#pragma unroll
        for (int kk = 0; kk < 2; ++kk) {
            const int csw = ((kk * 4 + qd) ^ (mr & 7)) * 8;
            const short8 a0 = *(const short8*)&Xs[(mh * 32 + mr) * 64 + csw];
            const short8 a1 = *(const short8*)&Xs[(mh * 32 + 16 + mr) * 64 + csw];
#pragma unroll
            for (int nt = 0; nt < 4; ++nt) {
                const short8 b = *(const short8*)&Bs[(nh * 64 + nt * 16 + mr) * 64 + csw];
                acc[0][nt] = __builtin_amdgcn_mfma_f32_16x16x32_bf16(a0, b, acc[0][nt], 0, 0, 0);
                acc[1][nt] = __builtin_amdgcn_mfma_f32_16x16x32_bf16(a1, b, acc[1][nt], 0, 0, 0);
            }
        }
        if (ktn >= KTILES) break;
        kt = ktn;
    }

    // epilogue: hardware f32 atomic adds (fire-and-forget), 32 per thread,
    // 32 contenders per (b,oc) address (one per iy slice).
    float* op = s_acc + (size_t)b0 * OCC;
#pragma unroll
    for (int mt = 0; mt < 2; ++mt)
#pragma unroll
        for (int nt = 0; nt < 4; ++nt)
#pragma unroll
            for (int r = 0; r < 4; ++r)
                atomAddF32(&op[(size_t)(mh * 32 + mt * 16 + qd * 4 + r) * OCC
                               + nh * 64 + nt * 16 + mr], acc[mt][nt][r]);
}

// ---------------- a: squash(s_acc) inline -> As; agreement GEMM; bij+softmax; write cwt.
// Block = 8 i's (301 blocks).
template<bool FIRST>
__global__ __launch_bounds__(256, 2)
void a_gemm(const unsigned short* __restrict__ xT, const float* __restrict__ s_acc,
            const unsigned short* __restrict__ Wbf, float* __restrict__ bij,
            unsigned short* __restrict__ cwt)
{
    __shared__ __align__(16) char smraw[128 * 68 * 4];      // 34816 B (staging aliased)
    unsigned short* As = (unsigned short*)smraw;            // [128 oc][64 b]
    unsigned short* Bx = (unsigned short*)(smraw + 16384);  // [64 (i,d)][64 b]
    float* Hs = (float*)smraw;                              // [128][68]

    const int tid = threadIdx.x;
    const int i0  = blockIdx.x * 8;
    const int ln  = tid & 63, wv = tid >> 6;
    const int mr  = ln & 15, qd = ln >> 4;

    f32x4 acc[2][4];
#pragma unroll
    for (int a = 0; a < 2; ++a)
#pragma unroll
        for (int b = 0; b < 4; ++b) acc[a][b] = (f32x4){0.f, 0.f, 0.f, 0.f};

    const int srow = tid >> 3, scol = tid & 7;
    const int ssw  = (scol ^ (srow & 7)) * 8;
    const unsigned short* bp0 = xT + (size_t)(i0 * 8 + srow) * 256 + (size_t)scol * 8;

    short8 vbx[2];
#pragma unroll
    for (int r = 0; r < 2; ++r) vbx[r] = *(const short8*)(bp0 + (size_t)r * 32 * 256);

    for (int bc = 0; bc < 4; ++bc) {
        __syncthreads();
        // As <- squash(s_acc) for this 64-b chunk, computed inline (s_acc is L2-hot)
        {
            const int rr0 = tid * 2;
#pragma unroll
            for (int rv = 0; rv < 2; ++rv) {
                const int rr = rr0 + rv;          // 0..511 : (o, bl)
                const int bl = rr & 63;
                const int o  = rr >> 6;
                const float* sp = s_acc + (size_t)(bc * 64 + bl) * OCC + o * 16;
                const float4 s0 = *(const float4*)(sp);
                const float4 s1 = *(const float4*)(sp + 4);
                const float4 s2 = *(const float4*)(sp + 8);
                const float4 s3 = *(const float4*)(sp + 12);
                float ms = s0.x*s0.x + s0.y*s0.y + s0.z*s0.z + s0.w*s0.w
                         + s1.x*s1.x + s1.y*s1.y + s1.z*s1.z + s1.w*s1.w
                         + s2.x*s2.x + s2.y*s2.y + s2.z*s2.z + s2.w*s2.w
                         + s3.x*s3.x + s3.y*s3.y + s3.z*s3.z + s3.w*s3.w;
                const float scale = sqrtf(ms) / (1.0f + ms);
                float vv[16] = { s0.x, s0.y, s0.z, s0.w, s1.x, s1.y, s1.z, s1.w,
                                 s2.x, s2.y, s2.z, s2.w, s3.x, s3.y, s3.z, s3.w };
                const int blq = bl >> 3, blr = bl & 7;
#pragma unroll
                for (int c = 0; c < 16; ++c) {
                    const int oc = o * 16 + c;
                    As[oc * 64 + ((blq ^ (oc & 7)) * 8) + blr] = f2bf(vv[c] * scale);
                }
            }
        }
#pragma unroll
        for (int r = 0; r < 2; ++r) *(short8*)&Bx[(r * 32 + srow) * 64 + ssw] = vbx[r];
        if (bc < 3) {
#pragma unroll
            for (int r = 0; r < 2; ++r) vbx[r] = *(const short8*)(bp0 + (size_t)r * 32 * 256 + (bc + 1) * 64);
        }
        __syncthreads();
#pragma unroll
        for (int kk = 0; kk < 2; ++kk) {
            const int csw = ((kk * 4 + qd) ^ (mr & 7)) * 8;
#pragma unroll
            for (int nt = 0; nt < 4; ++nt) {
                const short8 b = *(const short8*)&Bx[(nt * 16 + mr) * 64 + csw];
#pragma unroll
                for (int mt = 0; mt < 2; ++mt) {
                    const short8 a = *(const short8*)&As[((wv * 2 + mt) * 16 + mr) * 64 + csw];
                    acc[mt][nt] = __builtin_amdgcn_mfma_f32_16x16x32_bf16(a, b, acc[mt][nt], 0, 0, 0);
                }
            }
        }
    }

    __syncthreads();
#pragma unroll
    for (int mt = 0; mt < 2; ++mt)
#pragma unroll
        for (int nt = 0; nt < 4; ++nt)
#pragma unroll
            for (int r = 0; r < 4; ++r)
                Hs[((wv * 2 + mt) * 16 + qd * 4 + r) * 68 + nt * 16 + mr] = acc[mt][nt][r];
    __syncthreads();

    // phase 2: tid = il*32 + oo*4 + ch
    const int ch = tid & 3, oo = (tid >> 2) & 7, il = tid >> 5;
    const int ival = i0 + il;
    const int gi = (ival < IC) ? ival : IC - 1;
    const unsigned short* Wt = Wbf + (size_t)(oo * 16 + ch * 4) * KP + (size_t)gi * 8;

    float wreg[4][8];
#pragma unroll
    for (int c = 0; c < 4; ++c) {
        union { short8 v; unsigned short h[8]; } uw;
        uw.v = *(const short8*)(Wt + (size_t)c * KP);
#pragma unroll
        for (int j = 0; j < 8; ++j) wreg[c][j] = bf2f(uw.h[j]);
    }
    float p = 0.0f;
#pragma unroll
    for (int c = 0; c < 4; ++c) {
        const float* hr = &Hs[(oo * 16 + ch * 4 + c) * 68 + il * 8];
        const float4 h0 = *(const float4*)hr;
        const float4 h1 = *(const float4*)(hr + 4);
        p = fmaf(wreg[c][0], h0.x, p); p = fmaf(wreg[c][1], h0.y, p);
        p = fmaf(wreg[c][2], h0.z, p); p = fmaf(wreg[c][3], h0.w, p);
        p = fmaf(wreg[c][4], h1.x, p); p = fmaf(wreg[c][5], h1.y, p);
        p = fmaf(wreg[c][6], h1.z, p); p = fmaf(wreg[c][7], h1.w, p);
    }
    p += __shfl_xor(p, 1); p += __shfl_xor(p, 2);   // combine ch quarters
    const float anew = p * (1.0f / 256.0f);
    float bv = anew;
    if (!FIRST) bv += bij[gi * 8 + oo];
    float mx = bv;                                   // softmax over oo (bits 2..4)
    mx = fmaxf(mx, __shfl_xor(mx, 4));
    mx = fmaxf(mx, __shfl_xor(mx, 8));
    mx = fmaxf(mx, __shfl_xor(mx, 16));
    const float e = expf(bv - mx);
    float ss = e;
    ss += __shfl_xor(ss, 4); ss += __shfl_xor(ss, 8); ss += __shfl_xor(ss, 16);
    float cv = e / ss;
    if (ival >= IC) cv = 0.0f;                       // keep cwt pad rows zero
    if (ch == 0 && ival < IC) bij[ival * 8 + oo] = bv;
#pragma unroll
    for (int c = 0; c < 4; ++c) {
        union { short8 v; unsigned short h[8]; } o;
#pragma unroll
        for (int j = 0; j < 8; ++j) o.h[j] = f2bf(cv * wreg[c][j]);
        *(short8*)(cwt + (size_t)(oo * 16 + ch * 4 + c) * KP + (size_t)ival * 8) = o.v;
    }
}

// ---------------- final squash: out = squash(s_acc2). 8 blocks x 256 thr, 1 row each.
__global__ __launch_bounds__(256)
void squash_out(const float* __restrict__ s_acc, float* __restrict__ out)
{
    const int row = blockIdx.x * 256 + threadIdx.x;   // row = b*8+o, 0..2047
    const float* sp = s_acc + (size_t)(row >> 3) * OCC + (row & 7) * 16;
    const float4 s0 = *(const float4*)(sp);
    const float4 s1 = *(const float4*)(sp + 4);
    const float4 s2 = *(const float4*)(sp + 8);
    const float4 s3 = *(const float4*)(sp + 12);
    const float ms = s0.x*s0.x + s0.y*s0.y + s0.z*s0.z + s0.w*s0.w
                   + s1.x*s1.x + s1.y*s1.y + s1.z*s1.z + s1.w*s1.w
                   + s2.x*s2.x + s2.y*s2.y + s2.z*s2.z + s2.w*s2.w
                   + s3.x*s3.x + s3.y*s3.y + s3.z*s3.z + s3.w*s3.w;
    const float scale = sqrtf(ms) / (1.0f + ms);
    float4* op = (float4*)(out + (size_t)row * 16);
    op[0] = make_float4(s0.x*scale, s0.y*scale, s0.z*scale, s0.w*scale);
    op[1] = make_float4(s1.x*scale, s1.y*scale, s1.z*scale, s1.w*scale);
    op[2] = make_float4(s2.x*scale, s2.y*scale, s2.z*scale, s2.w*scale);
    op[3] = make_float4(s3.x*scale, s3.y*scale, s3.z*scale, s3.w*scale);
}

extern "C" void kernel_launch(void* const* d_in, const int* in_sizes, int n_in,
                              void* d_out, int out_size, void* d_ws, size_t ws_size,
                              hipStream_t stream)
{
    const float* x = (const float*)d_in[0];   // [256, 2401, 8]
    const float* W = (const float*)d_in[1];   // [2401, 8, 16, 8]
    float* out = (float*)d_out;               // [256, 8, 16]

    char* p = (char*)d_ws;
    float*          s_acc = (float*)p;          p += (size_t)3 * BSZ * OCC * 4;    // 393 KB (3 bufs)
    unsigned short* xT    = (unsigned short*)p; p += (size_t)KP * 256 * 2;         // 9.86 MB
    unsigned short* xB    = (unsigned short*)p; p += (size_t)256 * KP * 2;         // 9.86 MB
    unsigned short* Wbf   = (unsigned short*)p; p += (size_t)128 * KP * 2;         // 4.93 MB
    unsigned short* cwt   = (unsigned short*)p; p += (size_t)128 * KP * 2;         // 4.93 MB
    float*          bij   = (float*)p;                                             // 77 KB

    float* s0 = s_acc;
    float* s1 = s_acc + (size_t)BSZ * OCC;
    float* s2 = s_acc + (size_t)2 * BSZ * OCC;

    const dim3 sgrid(4, SNI);

    prep_kernel<<<1505, 256, 0, stream>>>(x, W, xT, xB, Wbf, cwt, s_acc);

    // iter 0
    s_gemm<<<sgrid, 256, 0, stream>>>(xB, cwt, s0);
    a_gemm<true><<<KTILES, 256, 0, stream>>>(xT, s0, Wbf, bij, cwt);
    // iter 1
    s_gemm<<<sgrid, 256, 0, stream>>>(xB, cwt, s1);
    a_gemm<false><<<KTILES, 256, 0, stream>>>(xT, s1, Wbf, bij, cwt);
    // iter 2 (final)
    s_gemm<<<sgrid, 256, 0, stream>>>(xB, cwt, s2);
    squash_out<<<8, 256, 0, stream>>>(s2, out);
}